// Round 2
// baseline (500.720 us; speedup 1.0000x reference)
//
#include <hip/hip_runtime.h>

typedef unsigned short u16;
typedef unsigned int u32;
typedef __attribute__((ext_vector_type(4))) float f32x4;
typedef __attribute__((ext_vector_type(8))) __bf16 bf16x8;
typedef __attribute__((ext_vector_type(4))) u16 u16x4;
typedef __attribute__((ext_vector_type(8))) u16 u16x8;

#define START_POS 3072
#define NKV 4096
#define HD_ 128
#define SEQ 1024
#define DIN_ 4096
#define DQKV 6144

__device__ __forceinline__ void gll16(const void* g, void* l) {
  __builtin_amdgcn_global_load_lds((const __attribute__((address_space(1))) u32*)g,
                                   (__attribute__((address_space(3))) u32*)l, 16, 0, 0);
}
__device__ __forceinline__ u16 f2bf(float f) {
  u32 u = __builtin_bit_cast(u32, f);
  return (u16)((u + 0x7fffu + ((u >> 16) & 1u)) >> 16);
}
__device__ __forceinline__ f32x4 mfma16(bf16x8 a, bf16x8 b, f32x4 c) {
  return __builtin_amdgcn_mfma_f32_16x16x32_bf16(a, b, c, 0, 0, 0);
}

// ---- transpose+convert W f32 [K=4096][N] -> Wt bf16 [N][4096] ----
__global__ __launch_bounds__(256) void wtrans(const float* __restrict__ W,
    u16* __restrict__ Wt, int N, int ntn, int row_off)
{
  __shared__ float T[64][68];
  int bid = blockIdx.x;
  int nt = bid % ntn, kt = bid / ntn;
  int t = threadIdx.x;
  int kl = t >> 4, nl4 = (t & 15) << 2;
#pragma unroll
  for (int r = 0; r < 4; r++) {
    int row = r * 16 + kl;   // 0..63: full 64-row coverage (r1 bug: only 16 rows)
    f32x4 v = *(const f32x4*)(W + (size_t)(kt * 64 + row) * N + nt * 64 + nl4);
    T[row][nl4] = v[0]; T[row][nl4 + 1] = v[1]; T[row][nl4 + 2] = v[2]; T[row][nl4 + 3] = v[3];
  }
  __syncthreads();
  int nl = t >> 2, k0 = (t & 3) << 4;
  u16x8 lo, hi;
#pragma unroll
  for (int j = 0; j < 8; j++) lo[j] = f2bf(T[k0 + j][nl]);
#pragma unroll
  for (int j = 0; j < 8; j++) hi[j] = f2bf(T[k0 + 8 + j][nl]);
  u16* dst = Wt + (size_t)(row_off + nt * 64 + nl) * 4096 + kt * 64 + k0;
  *(u16x8*)dst = lo;
  *(u16x8*)(dst + 8) = hi;
}

// ---- f32 -> bf16 convert ----
__global__ __launch_bounds__(256) void cvt_bf16(const float* __restrict__ src,
    u16* __restrict__ dst, int n4)
{
  int i = blockIdx.x * 256 + threadIdx.x;
  if (i >= n4) return;
  f32x4 v = *(const f32x4*)(src + (size_t)i * 4);
  u16x4 o;
#pragma unroll
  for (int j = 0; j < 4; j++) o[j] = f2bf(v[j]);
  *(u16x4*)(dst + (size_t)i * 4) = o;
}

// ---- bf16 GEMM: C[M][N] f32 = A[M][K] * Bt[N][K], 128x128 tile, BK=32 ----
__global__ __launch_bounds__(256) void gemm_bt(
    const u16* __restrict__ A, const u16* __restrict__ Bt,
    float* __restrict__ C, int N, int K, int nbx)
{
  __shared__ u16 As[128 * 32];
  __shared__ u16 Bs[128 * 32];
  int nwg = (int)gridDim.x;
  int orig = blockIdx.x;
  int q8 = nwg >> 3, r8 = nwg & 7;
  int xcd = orig & 7, jj = orig >> 3;
  int wgid = (xcd < r8 ? xcd * (q8 + 1) : r8 * (q8 + 1) + (xcd - r8) * q8) + jj;
  int by = wgid / nbx, bx = wgid % nbx;
  int tid = threadIdx.x, lane = tid & 63, wid = tid >> 6;
  int wr = wid >> 1, wc = wid & 1;
  int c = lane & 15, hh = lane >> 4;
  int lrow = wid * 16 + (lane >> 2);
  int ksl = (lane & 3) << 3;
  const u16* aS0 = A + (size_t)(by * 128 + lrow) * K + ksl;
  const u16* bS0 = Bt + (size_t)(bx * 128 + lrow) * K + ksl;
  u16* aL0 = As + wid * 512;
  u16* bL0 = Bs + wid * 512;
  f32x4 acc[4][4] = {};
  for (int k0 = 0; k0 < K; k0 += 32) {
    gll16(aS0 + k0, aL0);
    gll16(aS0 + (size_t)64 * K + k0, aL0 + 2048);
    gll16(bS0 + k0, bL0);
    gll16(bS0 + (size_t)64 * K + k0, bL0 + 2048);
    __syncthreads();
    bf16x8 af[4], bf[4];
#pragma unroll
    for (int i = 0; i < 4; i++) {
      af[i] = *(const bf16x8*)(As + (wr * 64 + i * 16 + c) * 32 + hh * 8);
      bf[i] = *(const bf16x8*)(Bs + (wc * 64 + i * 16 + c) * 32 + hh * 8);
    }
#pragma unroll
    for (int mi = 0; mi < 4; mi++)
#pragma unroll
      for (int ni = 0; ni < 4; ni++)
        acc[mi][ni] = mfma16(af[mi], bf[ni], acc[mi][ni]);
    __syncthreads();
  }
  int row0 = by * 128 + wr * 64 + hh * 4;
  int col0 = bx * 128 + wc * 64 + c;
#pragma unroll
  for (int mi = 0; mi < 4; mi++)
#pragma unroll
    for (int ni = 0; ni < 4; ni++)
#pragma unroll
      for (int i = 0; i < 4; i++)
        C[(size_t)(row0 + mi * 16 + i) * N + col0 + ni * 16] = acc[mi][ni][i];
}

// ---- RoPE on q part of qkv -> qb bf16 [32][1024][128] ----
__global__ __launch_bounds__(256) void rope_q(const float* __restrict__ qkv,
    const float* __restrict__ cosb, const float* __restrict__ sinb, u16* __restrict__ qb)
{
  int tid = blockIdx.x * 256 + threadIdx.x;  // 524288
  int dq = tid & 15, h = (tid >> 4) & 31, s = tid >> 9;
  int d = dq << 2;
  const float* base = qkv + (size_t)s * DQKV + h * HD_ + d;
  f32x4 a = *(const f32x4*)base;
  f32x4 b2 = *(const f32x4*)(base + 64);
  f32x4 cc = *(const f32x4*)(cosb + (size_t)(START_POS + s) * HD_ + d);
  f32x4 sn = *(const f32x4*)(sinb + (size_t)(START_POS + s) * HD_ + d);
  u16x4 o1, o2;
#pragma unroll
  for (int i = 0; i < 4; i++) {
    o1[i] = f2bf(a[i] * cc[i] - b2[i] * sn[i]);
    o2[i] = f2bf(b2[i] * cc[i] + a[i] * sn[i]);
  }
  u16* dst = qb + ((size_t)h * SEQ + s) * HD_ + d;
  *(u16x4*)dst = o1;
  *(u16x4*)(dst + 64) = o2;
}

// ---- RoPE on k part -> keys f32 output (pos>=3072) + kb bf16 ----
__global__ __launch_bounds__(256) void rope_k(const float* __restrict__ qkv,
    const float* __restrict__ cosb, const float* __restrict__ sinb,
    float* __restrict__ keys, u16* __restrict__ kbb)
{
  int tid = blockIdx.x * 256 + threadIdx.x;  // 131072
  int dq = tid & 15, g = (tid >> 4) & 7, s = tid >> 7;
  int d = dq << 2;
  const float* base = qkv + (size_t)s * DQKV + DIN_ + g * HD_ + d;
  f32x4 a = *(const f32x4*)base;
  f32x4 b2 = *(const f32x4*)(base + 64);
  f32x4 cc = *(const f32x4*)(cosb + (size_t)(START_POS + s) * HD_ + d);
  f32x4 sn = *(const f32x4*)(sinb + (size_t)(START_POS + s) * HD_ + d);
  f32x4 o1, o2;
  u16x4 p1, p2;
#pragma unroll
  for (int i = 0; i < 4; i++) {
    o1[i] = a[i] * cc[i] - b2[i] * sn[i];
    o2[i] = b2[i] * cc[i] + a[i] * sn[i];
    p1[i] = f2bf(o1[i]);
    p2[i] = f2bf(o2[i]);
  }
  size_t off = ((size_t)g * NKV + START_POS + s) * HD_ + d;
  *(f32x4*)(keys + off) = o1;
  *(f32x4*)(keys + off + 64) = o2;
  *(u16x4*)(kbb + off) = p1;
  *(u16x4*)(kbb + off + 64) = p2;
}

// ---- copy v part -> values f32 output (pos>=3072) ----
__global__ __launch_bounds__(256) void copy_vnew(const float* __restrict__ qkv,
    float* __restrict__ values)
{
  int tid = blockIdx.x * 256 + threadIdx.x;  // 262144
  int dq = tid & 31, g = (tid >> 5) & 7, s = tid >> 8;
  int d = dq << 2;
  f32x4 v = *(const f32x4*)(qkv + (size_t)s * DQKV + DIN_ + 1024 + g * HD_ + d);
  *(f32x4*)(values + ((size_t)g * NKV + START_POS + s) * HD_ + d) = v;
}

// ---- copy prev_k/prev_v -> keys/values f32 outputs + kb bf16 ----
__global__ __launch_bounds__(256) void prev_copy(const float* __restrict__ pk,
    const float* __restrict__ pv, float* __restrict__ keys, float* __restrict__ values,
    u16* __restrict__ kbb)
{
  int idx = blockIdx.x * 256 + threadIdx.x;  // 786432 quads
  int d4 = idx & 31;
  int rest = idx >> 5;
  int p = rest % 3072, g = rest / 3072;
  f32x4 kq = *(const f32x4*)(pk + (size_t)idx * 4);
  f32x4 vq = *(const f32x4*)(pv + (size_t)idx * 4);
  size_t off = ((size_t)g * NKV + p) * HD_ + d4 * 4;
  *(f32x4*)(keys + off) = kq;
  *(f32x4*)(values + off) = vq;
  u16x4 kb4;
#pragma unroll
  for (int i = 0; i < 4; i++) kb4[i] = f2bf(kq[i]);
  *(u16x4*)(kbb + off) = kb4;
}

// ---- build vT bf16 [8][128][4096] from prev_v (pos<3072) / qkv v-cols ----
__global__ __launch_bounds__(256) void vtrans(const float* __restrict__ pv,
    const float* __restrict__ qkv, u16* __restrict__ vT)
{
  __shared__ float T[64][68];
  int bid = blockIdx.x;  // 1024 = g(8) * pt(64) * dt(2)
  int dt = bid & 1, pt = (bid >> 1) & 63, g = bid >> 7;
  int t = threadIdx.x;
  int pl = t >> 4, dl4 = (t & 15) << 2;
#pragma unroll
  for (int r = 0; r < 4; r++) {
    int row = r * 16 + pl;   // 0..63: full coverage (r1 bug: only 16 rows)
    int pos = pt * 64 + row;
    f32x4 v;
    if (pos < START_POS)
      v = *(const f32x4*)(pv + ((size_t)g * START_POS + pos) * HD_ + dt * 64 + dl4);
    else
      v = *(const f32x4*)(qkv + (size_t)(pos - START_POS) * DQKV + 5120 + g * HD_ + dt * 64 + dl4);
    T[row][dl4] = v[0]; T[row][dl4 + 1] = v[1]; T[row][dl4 + 2] = v[2]; T[row][dl4 + 3] = v[3];
  }
  __syncthreads();
  int dl = t >> 2, p0 = (t & 3) << 4;
  u16x8 lo, hi;
#pragma unroll
  for (int j = 0; j < 8; j++) lo[j] = f2bf(T[p0 + j][dl]);
#pragma unroll
  for (int j = 0; j < 8; j++) hi[j] = f2bf(T[p0 + 8 + j][dl]);
  u16* dst = vT + ((size_t)g * HD_ + dt * 64 + dl) * NKV + pt * 64 + p0;
  *(u16x8*)dst = lo;
  *(u16x8*)(dst + 8) = hi;
}

// ---- flash attention: 256 blocks, 4 waves x 32 q-rows ----
__global__ __launch_bounds__(256, 2) void attn_fwd(
    const u16* __restrict__ qb, const u16* __restrict__ kb,
    const u16* __restrict__ vT, u16* __restrict__ ctxb)
{
  __shared__ u16 Ks[64 * 128];
  __shared__ u16 Vs[128 * 64];
  __shared__ u16 Ps[4 * 32 * 80];  // per-wave [32 rows][stride 80 elems]
  const float C2 = 0.12751744f;    // log2(e)/sqrt(128)
  int bid = blockIdx.x;
  int g = bid & 7, j = bid >> 3;   // XCD x owns group g=x
  int h = g * 4 + (j >> 3), qt = j & 7;
  int tid = threadIdx.x, lane = tid & 63, w = tid >> 6;
  int c = lane & 15, hh = lane >> 4;
  int qr0 = qt * 128 + w * 32;
  bf16x8 Qf[2][4];
#pragma unroll
  for (int rg = 0; rg < 2; rg++)
#pragma unroll
    for (int ks = 0; ks < 4; ks++)
      Qf[rg][ks] = *(const bf16x8*)(qb + ((size_t)(h * 1024 + qr0 + rg * 16 + c)) * 128 + ks * 32 + hh * 8);
  f32x4 O[2][8] = {};
  float Mx[2][4], Ls[2][4];
#pragma unroll
  for (int rg = 0; rg < 2; rg++)
#pragma unroll
    for (int i = 0; i < 4; i++) { Mx[rg][i] = -1e30f; Ls[rg][i] = 0.f; }
  u16* Pw = Ps + w * 32 * 80;
  int nt = 50 + 2 * qt;
  for (int t = 0; t < nt; t++) {
    // stage K [64][128] and V^T [128][64], XOR-swizzled slots via pre-swizzled source
#pragma unroll
    for (int r = 0; r < 4; r++) {
      int s = w * 256 + r * 64 + lane;
      int krow = s >> 4, sl = s & 15;
      int slx = sl ^ (krow & 7);
      gll16(kb + ((size_t)(g * 4096 + t * 64 + krow)) * 128 + slx * 8, Ks + (w * 256 + r * 64) * 8);
      int d = s >> 3, sl2 = s & 7;
      int slx2 = sl2 ^ (d & 7);
      gll16(vT + ((size_t)(g * 128 + d)) * 4096 + t * 64 + slx2 * 8, Vs + (w * 256 + r * 64) * 8);
    }
    __syncthreads();
    // S = Q K^T
    f32x4 S[2][4] = {};
#pragma unroll
    for (int ks = 0; ks < 4; ks++) {
      bf16x8 kf[4];
#pragma unroll
      for (int kvf = 0; kvf < 4; kvf++) {
        int kr = kvf * 16 + c;
        int slx = (ks * 4 + hh) ^ (kr & 7);
        kf[kvf] = *(const bf16x8*)(Ks + kr * 128 + slx * 8);
      }
#pragma unroll
      for (int rg = 0; rg < 2; rg++)
#pragma unroll
        for (int kvf = 0; kvf < 4; kvf++)
          S[rg][kvf] = mfma16(Qf[rg][ks], kf[kvf], S[rg][kvf]);
    }
    // causal mask (only near diagonal)
    if (t * 64 + 63 > START_POS + qr0) {
#pragma unroll
      for (int rg = 0; rg < 2; rg++)
#pragma unroll
        for (int kvf = 0; kvf < 4; kvf++)
#pragma unroll
          for (int i = 0; i < 4; i++) {
            int kv = t * 64 + kvf * 16 + c;
            int qi = qr0 + rg * 16 + hh * 4 + i;
            if (kv > START_POS + qi) S[rg][kvf][i] = -1e30f;
          }
    }
    // online softmax
#pragma unroll
    for (int rg = 0; rg < 2; rg++) {
      float mt[4], al[4], rs[4];
#pragma unroll
      for (int i = 0; i < 4; i++)
        mt[i] = fmaxf(fmaxf(S[rg][0][i], S[rg][1][i]), fmaxf(S[rg][2][i], S[rg][3][i]));
#pragma unroll
      for (int m = 1; m < 16; m <<= 1)
#pragma unroll
        for (int i = 0; i < 4; i++)
          mt[i] = fmaxf(mt[i], __shfl_xor(mt[i], m));
#pragma unroll
      for (int i = 0; i < 4; i++) {
        float Mn = fmaxf(Mx[rg][i], mt[i]);
        al[i] = exp2f((Mx[rg][i] - Mn) * C2);
        Mx[rg][i] = Mn;
        rs[i] = 0.f;
      }
#pragma unroll
      for (int kvf = 0; kvf < 4; kvf++)
#pragma unroll
        for (int i = 0; i < 4; i++) {
          float p = exp2f((S[rg][kvf][i] - Mx[rg][i]) * C2);
          rs[i] += p;
          int prow = rg * 16 + hh * 4 + i;
          int pb = prow * 160 + ((kvf * 32 + c * 2) ^ ((prow & 7) << 4));
          *(u16*)((char*)Pw + pb) = f2bf(p);
        }
#pragma unroll
      for (int m = 1; m < 16; m <<= 1)
#pragma unroll
        for (int i = 0; i < 4; i++)
          rs[i] += __shfl_xor(rs[i], m);
#pragma unroll
      for (int i = 0; i < 4; i++)
        Ls[rg][i] = Ls[rg][i] * al[i] + rs[i];
#pragma unroll
      for (int dt = 0; dt < 8; dt++)
#pragma unroll
        for (int i = 0; i < 4; i++)
          O[rg][dt][i] *= al[i];
    }
    // cross-lane P exchange through LDS: force wave-level LDS drain
    asm volatile("s_waitcnt lgkmcnt(0)" ::: "memory");
    __builtin_amdgcn_sched_barrier(0);
    // O += P V
#pragma unroll
    for (int ks2 = 0; ks2 < 2; ks2++) {
      bf16x8 pa[2];
#pragma unroll
      for (int rg = 0; rg < 2; rg++) {
        int prow = rg * 16 + c;
        int pb = prow * 160 + ((ks2 * 64 + hh * 16) ^ ((prow & 7) << 4));
        pa[rg] = *(const bf16x8*)((const char*)Pw + pb);
      }
#pragma unroll
      for (int dt = 0; dt < 8; dt++) {
        int d = dt * 16 + c;
        int slx = (ks2 * 4 + hh) ^ (d & 7);
        bf16x8 vf = *(const bf16x8*)(Vs + d * 64 + slx * 8);
        O[0][dt] = mfma16(pa[0], vf, O[0][dt]);
        O[1][dt] = mfma16(pa[1], vf, O[1][dt]);
      }
    }
    __syncthreads();
  }
  // epilogue: ctx = O / L -> bf16 [s][h*128+d]
#pragma unroll
  for (int rg = 0; rg < 2; rg++) {
    float inv[4];
#pragma unroll
    for (int i = 0; i < 4; i++) inv[i] = 1.0f / Ls[rg][i];
#pragma unroll
    for (int dt = 0; dt < 8; dt++)
#pragma unroll
      for (int i = 0; i < 4; i++) {
        int qrow = qr0 + rg * 16 + hh * 4 + i;
        int col = h * 128 + dt * 16 + c;
        ctxb[(size_t)qrow * 4096 + col] = f2bf(O[rg][dt][i] * inv[i]);
      }
  }
}

extern "C" void kernel_launch(void* const* d_in, const int* in_sizes, int n_in,
                              void* d_out, int out_size, void* d_ws, size_t ws_size,
                              hipStream_t stream) {
  const float* x      = (const float*)d_in[0];
  const float* cosb   = (const float*)d_in[2];
  const float* sinb   = (const float*)d_in[3];
  const float* prev_k = (const float*)d_in[5];
  const float* prev_v = (const float*)d_in[6];
  const float* Wq     = (const float*)d_in[7];
  const float* Wk     = (const float*)d_in[8];
  const float* Wv     = (const float*)d_in[9];
  const float* Wo     = (const float*)d_in[10];

  // workspace layout (~151 MB)
  u16* Wt_proj = (u16*)d_ws;                                  // [6144][4096] bf16
  u16* Wt_out  = Wt_proj + (size_t)6144 * 4096;               // [4096][4096] bf16
  u16* xb      = Wt_out + (size_t)4096 * 4096;                // [1024][4096] bf16
  float* qkv   = (float*)(xb + (size_t)1024 * 4096);          // [1024][6144] f32
  u16* qb      = (u16*)(qkv + (size_t)1024 * 6144);           // [32][1024][128]
  u16* kbb     = qb + (size_t)32 * 1024 * 128;                // [8][4096][128]
  u16* vT      = kbb + (size_t)8 * 4096 * 128;                // [8][128][4096]
  u16* ctxb    = vT + (size_t)8 * 4096 * 128;                 // [1024][4096]

  float* outp   = (float*)d_out;
  float* keys   = outp + (size_t)4194304;
  float* values = outp + (size_t)8388608;

  wtrans<<<4096, 256, 0, stream>>>(Wq, Wt_proj, 4096, 64, 0);
  wtrans<<<1024, 256, 0, stream>>>(Wk, Wt_proj, 1024, 16, 4096);
  wtrans<<<1024, 256, 0, stream>>>(Wv, Wt_proj, 1024, 16, 5120);
  wtrans<<<4096, 256, 0, stream>>>(Wo, Wt_out, 4096, 64, 0);
  cvt_bf16<<<4096, 256, 0, stream>>>(x, xb, 1048576);

  gemm_bt<<<384, 256, 0, stream>>>(xb, Wt_proj, qkv, 6144, 4096, 48);

  rope_q<<<2048, 256, 0, stream>>>(qkv, cosb, sinb, qb);
  rope_k<<<512, 256, 0, stream>>>(qkv, cosb, sinb, keys, kbb);
  copy_vnew<<<1024, 256, 0, stream>>>(qkv, values);
  prev_copy<<<3072, 256, 0, stream>>>(prev_k, prev_v, keys, values, kbb);
  vtrans<<<1024, 256, 0, stream>>>(prev_v, qkv, vT);

  attn_fwd<<<256, 256, 0, stream>>>(qb, kbb, vT, ctxb);

  gemm_bt<<<256, 256, 0, stream>>>(ctxb, Wt_out, outp, 4096, 4096, 32);
}

// Round 3
// 454.900 us; speedup vs baseline: 1.1007x; 1.1007x over previous
//
#include <hip/hip_runtime.h>

typedef unsigned short u16;
typedef unsigned int u32;
typedef __attribute__((ext_vector_type(4))) float f32x4;
typedef __attribute__((ext_vector_type(8))) __bf16 bf16x8;
typedef __attribute__((ext_vector_type(4))) u16 u16x4;
typedef __attribute__((ext_vector_type(8))) u16 u16x8;

#define START_POS 3072
#define NKV 4096
#define HD_ 128
#define SEQ 1024
#define DIN_ 4096
#define DQKV 6144

__device__ __forceinline__ void gll16(const void* g, void* l) {
  __builtin_amdgcn_global_load_lds((const __attribute__((address_space(1))) u32*)g,
                                   (__attribute__((address_space(3))) u32*)l, 16, 0, 0);
}
__device__ __forceinline__ u16 f2bf(float f) {
  u32 u = __builtin_bit_cast(u32, f);
  return (u16)((u + 0x7fffu + ((u >> 16) & 1u)) >> 16);
}
__device__ __forceinline__ f32x4 mfma16(bf16x8 a, bf16x8 b, f32x4 c) {
  return __builtin_amdgcn_mfma_f32_16x16x32_bf16(a, b, c, 0, 0, 0);
}

// ---- transpose+convert W f32 [K=4096][N] -> Wt bf16 [N][4096] ----
__global__ __launch_bounds__(256) void wtrans(const float* __restrict__ W,
    u16* __restrict__ Wt, int N, int ntn, int row_off)
{
  __shared__ float T[64][68];
  int bid = blockIdx.x;
  int nt = bid % ntn, kt = bid / ntn;
  int t = threadIdx.x;
  int kl = t >> 4, nl4 = (t & 15) << 2;
#pragma unroll
  for (int r = 0; r < 4; r++) {
    int row = r * 16 + kl;
    f32x4 v = *(const f32x4*)(W + (size_t)(kt * 64 + row) * N + nt * 64 + nl4);
    T[row][nl4] = v[0]; T[row][nl4 + 1] = v[1]; T[row][nl4 + 2] = v[2]; T[row][nl4 + 3] = v[3];
  }
  __syncthreads();
  int nl = t >> 2, k0 = (t & 3) << 4;
  u16x8 lo, hi;
#pragma unroll
  for (int j = 0; j < 8; j++) lo[j] = f2bf(T[k0 + j][nl]);
#pragma unroll
  for (int j = 0; j < 8; j++) hi[j] = f2bf(T[k0 + 8 + j][nl]);
  u16* dst = Wt + (size_t)(row_off + nt * 64 + nl) * 4096 + kt * 64 + k0;
  *(u16x8*)dst = lo;
  *(u16x8*)(dst + 8) = hi;
}

// ---- f32 -> bf16 convert ----
__global__ __launch_bounds__(256) void cvt_bf16(const float* __restrict__ src,
    u16* __restrict__ dst, int n4)
{
  int i = blockIdx.x * 256 + threadIdx.x;
  if (i >= n4) return;
  f32x4 v = *(const f32x4*)(src + (size_t)i * 4);
  u16x4 o;
#pragma unroll
  for (int j = 0; j < 4; j++) o[j] = f2bf(v[j]);
  *(u16x4*)(dst + (size_t)i * 4) = o;
}

// ---- bf16 GEMM: C[M][N] f32 = A[M][K] * Bt[N][K], 128x128 tile, BK=32 ----
__global__ __launch_bounds__(256) void gemm_bt(
    const u16* __restrict__ A, const u16* __restrict__ Bt,
    float* __restrict__ C, int N, int K, int nbx)
{
  __shared__ u16 As[128 * 32];
  __shared__ u16 Bs[128 * 32];
  int nwg = (int)gridDim.x;
  int orig = blockIdx.x;
  int q8 = nwg >> 3, r8 = nwg & 7;
  int xcd = orig & 7, jj = orig >> 3;
  int wgid = (xcd < r8 ? xcd * (q8 + 1) : r8 * (q8 + 1) + (xcd - r8) * q8) + jj;
  int by = wgid / nbx, bx = wgid % nbx;
  int tid = threadIdx.x, lane = tid & 63, wid = tid >> 6;
  int wr = wid >> 1, wc = wid & 1;
  int c = lane & 15, hh = lane >> 4;
  int lrow = wid * 16 + (lane >> 2);
  int ksl = (lane & 3) << 3;
  const u16* aS0 = A + (size_t)(by * 128 + lrow) * K + ksl;
  const u16* bS0 = Bt + (size_t)(bx * 128 + lrow) * K + ksl;
  u16* aL0 = As + wid * 512;
  u16* bL0 = Bs + wid * 512;
  f32x4 acc[4][4] = {};
  for (int k0 = 0; k0 < K; k0 += 32) {
    gll16(aS0 + k0, aL0);
    gll16(aS0 + (size_t)64 * K + k0, aL0 + 2048);
    gll16(bS0 + k0, bL0);
    gll16(bS0 + (size_t)64 * K + k0, bL0 + 2048);
    __syncthreads();
    bf16x8 af[4], bf[4];
#pragma unroll
    for (int i = 0; i < 4; i++) {
      af[i] = *(const bf16x8*)(As + (wr * 64 + i * 16 + c) * 32 + hh * 8);
      bf[i] = *(const bf16x8*)(Bs + (wc * 64 + i * 16 + c) * 32 + hh * 8);
    }
#pragma unroll
    for (int mi = 0; mi < 4; mi++)
#pragma unroll
      for (int ni = 0; ni < 4; ni++)
        acc[mi][ni] = mfma16(af[mi], bf[ni], acc[mi][ni]);
    __syncthreads();
  }
  int row0 = by * 128 + wr * 64 + hh * 4;
  int col0 = bx * 128 + wc * 64 + c;
#pragma unroll
  for (int mi = 0; mi < 4; mi++)
#pragma unroll
    for (int ni = 0; ni < 4; ni++)
#pragma unroll
      for (int i = 0; i < 4; i++)
        C[(size_t)(row0 + mi * 16 + i) * N + col0 + ni * 16] = acc[mi][ni][i];
}

// ---- RoPE on q part of qkv -> qb bf16 [32][1024][128] ----
__global__ __launch_bounds__(256) void rope_q(const float* __restrict__ qkv,
    const float* __restrict__ cosb, const float* __restrict__ sinb, u16* __restrict__ qb)
{
  int tid = blockIdx.x * 256 + threadIdx.x;  // 524288
  int dq = tid & 15, h = (tid >> 4) & 31, s = tid >> 9;
  int d = dq << 2;
  const float* base = qkv + (size_t)s * DQKV + h * HD_ + d;
  f32x4 a = *(const f32x4*)base;
  f32x4 b2 = *(const f32x4*)(base + 64);
  f32x4 cc = *(const f32x4*)(cosb + (size_t)(START_POS + s) * HD_ + d);
  f32x4 sn = *(const f32x4*)(sinb + (size_t)(START_POS + s) * HD_ + d);
  u16x4 o1, o2;
#pragma unroll
  for (int i = 0; i < 4; i++) {
    o1[i] = f2bf(a[i] * cc[i] - b2[i] * sn[i]);
    o2[i] = f2bf(b2[i] * cc[i] + a[i] * sn[i]);
  }
  u16* dst = qb + ((size_t)h * SEQ + s) * HD_ + d;
  *(u16x4*)dst = o1;
  *(u16x4*)(dst + 64) = o2;
}

// ---- RoPE on k part -> keys f32 output (pos>=3072) + kb bf16 ----
__global__ __launch_bounds__(256) void rope_k(const float* __restrict__ qkv,
    const float* __restrict__ cosb, const float* __restrict__ sinb,
    float* __restrict__ keys, u16* __restrict__ kbb)
{
  int tid = blockIdx.x * 256 + threadIdx.x;  // 131072
  int dq = tid & 15, g = (tid >> 4) & 7, s = tid >> 7;
  int d = dq << 2;
  const float* base = qkv + (size_t)s * DQKV + DIN_ + g * HD_ + d;
  f32x4 a = *(const f32x4*)base;
  f32x4 b2 = *(const f32x4*)(base + 64);
  f32x4 cc = *(const f32x4*)(cosb + (size_t)(START_POS + s) * HD_ + d);
  f32x4 sn = *(const f32x4*)(sinb + (size_t)(START_POS + s) * HD_ + d);
  f32x4 o1, o2;
  u16x4 p1, p2;
#pragma unroll
  for (int i = 0; i < 4; i++) {
    o1[i] = a[i] * cc[i] - b2[i] * sn[i];
    o2[i] = b2[i] * cc[i] + a[i] * sn[i];
    p1[i] = f2bf(o1[i]);
    p2[i] = f2bf(o2[i]);
  }
  size_t off = ((size_t)g * NKV + START_POS + s) * HD_ + d;
  *(f32x4*)(keys + off) = o1;
  *(f32x4*)(keys + off + 64) = o2;
  *(u16x4*)(kbb + off) = p1;
  *(u16x4*)(kbb + off + 64) = p2;
}

// ---- copy v part -> values f32 output (pos>=3072) ----
__global__ __launch_bounds__(256) void copy_vnew(const float* __restrict__ qkv,
    float* __restrict__ values)
{
  int tid = blockIdx.x * 256 + threadIdx.x;  // 262144
  int dq = tid & 31, g = (tid >> 5) & 7, s = tid >> 8;
  int d = dq << 2;
  f32x4 v = *(const f32x4*)(qkv + (size_t)s * DQKV + DIN_ + 1024 + g * HD_ + d);
  *(f32x4*)(values + ((size_t)g * NKV + START_POS + s) * HD_ + d) = v;
}

// ---- copy prev_k/prev_v -> keys/values f32 outputs + kb bf16 ----
__global__ __launch_bounds__(256) void prev_copy(const float* __restrict__ pk,
    const float* __restrict__ pv, float* __restrict__ keys, float* __restrict__ values,
    u16* __restrict__ kbb)
{
  int idx = blockIdx.x * 256 + threadIdx.x;  // 786432 quads
  int d4 = idx & 31;
  int rest = idx >> 5;
  int p = rest % 3072, g = rest / 3072;
  f32x4 kq = *(const f32x4*)(pk + (size_t)idx * 4);
  f32x4 vq = *(const f32x4*)(pv + (size_t)idx * 4);
  size_t off = ((size_t)g * NKV + p) * HD_ + d4 * 4;
  *(f32x4*)(keys + off) = kq;
  *(f32x4*)(values + off) = vq;
  u16x4 kb4;
#pragma unroll
  for (int i = 0; i < 4; i++) kb4[i] = f2bf(kq[i]);
  *(u16x4*)(kbb + off) = kb4;
}

// ---- build vT bf16 [8][128][4096] from prev_v (pos<3072) / qkv v-cols ----
__global__ __launch_bounds__(256) void vtrans(const float* __restrict__ pv,
    const float* __restrict__ qkv, u16* __restrict__ vT)
{
  __shared__ float T[64][68];
  int bid = blockIdx.x;  // 1024 = g(8) * pt(64) * dt(2)
  int dt = bid & 1, pt = (bid >> 1) & 63, g = bid >> 7;
  int t = threadIdx.x;
  int pl = t >> 4, dl4 = (t & 15) << 2;
#pragma unroll
  for (int r = 0; r < 4; r++) {
    int row = r * 16 + pl;
    int pos = pt * 64 + row;
    f32x4 v;
    if (pos < START_POS)
      v = *(const f32x4*)(pv + ((size_t)g * START_POS + pos) * HD_ + dt * 64 + dl4);
    else
      v = *(const f32x4*)(qkv + (size_t)(pos - START_POS) * DQKV + 5120 + g * HD_ + dt * 64 + dl4);
    T[row][dl4] = v[0]; T[row][dl4 + 1] = v[1]; T[row][dl4 + 2] = v[2]; T[row][dl4 + 3] = v[3];
  }
  __syncthreads();
  int dl = t >> 2, p0 = (t & 3) << 4;
  u16x8 lo, hi;
#pragma unroll
  for (int j = 0; j < 8; j++) lo[j] = f2bf(T[p0 + j][dl]);
#pragma unroll
  for (int j = 0; j < 8; j++) hi[j] = f2bf(T[p0 + 8 + j][dl]);
  u16* dst = vT + ((size_t)g * HD_ + dt * 64 + dl) * NKV + pt * 64 + p0;
  *(u16x8*)dst = lo;
  *(u16x8*)(dst + 8) = hi;
}

// ---- flash attention v2: 512 blocks (h x 16 q-tiles of 64), 4 waves x 16 q-rows,
// ---- double-buffered K/V LDS with prefetch-before-compute (T3 2-phase minimum) ----
__global__ __launch_bounds__(256, 2) void attn_fwd(
    const u16* __restrict__ qb, const u16* __restrict__ kb,
    const u16* __restrict__ vT, u16* __restrict__ ctxb)
{
  __shared__ u16 Ks[2 * 64 * 128];
  __shared__ u16 Vs[2 * 128 * 64];
  __shared__ u16 Ps[4 * 16 * 80];  // per-wave [16 rows][stride 80 elems]
  const float C2 = 0.12751744f;    // log2(e)/sqrt(128)
  int bid = blockIdx.x;
  int g = bid & 7, j = bid >> 3;   // XCD x owns group g=x; j in [0,64)
  int h = g * 4 + (j >> 4), qt = j & 15;
  int tid = threadIdx.x, lane = tid & 63, w = tid >> 6;
  int c = lane & 15, hh = lane >> 4;
  int qw0 = qt * 64 + w * 16;      // this wave's first q row
  bf16x8 Qf[4];
#pragma unroll
  for (int ks = 0; ks < 4; ks++)
    Qf[ks] = *(const bf16x8*)(qb + ((size_t)(h * 1024 + qw0 + c)) * 128 + ks * 32 + hh * 8);
  f32x4 O[8] = {};
  float Mx[4], Ls[4];
#pragma unroll
  for (int i = 0; i < 4; i++) { Mx[i] = -1e30f; Ls[i] = 0.f; }
  u16* Pw = Ps + w * 16 * 80;
  int nt = 49 + qt;

#define STAGE_KV(tt, bo) do { \
  _Pragma("unroll") \
  for (int r = 0; r < 4; r++) { \
    int s = w * 256 + r * 64 + lane; \
    int krow = s >> 4, sl = s & 15; \
    int slx = sl ^ (krow & 7); \
    gll16(kb + ((size_t)(g * 4096 + (tt) * 64 + krow)) * 128 + slx * 8, Ks + (bo) + (w * 256 + r * 64) * 8); \
    int d = s >> 3, sl2 = s & 7; \
    int slx2 = sl2 ^ (d & 7); \
    gll16(vT + ((size_t)(g * 128 + d)) * 4096 + (tt) * 64 + slx2 * 8, Vs + (bo) + (w * 256 + r * 64) * 8); \
  } \
} while (0)

  int cur = 0;
  STAGE_KV(0, 0);
  __syncthreads();  // drains vmcnt(0): tile 0 resident
  for (int t = 0; t < nt; t++) {
    // issue next tile's loads into the other buffer BEFORE compute (latency hides under compute)
    if (t + 1 < nt) STAGE_KV(t + 1, (cur ^ 1) * 8192);
    const u16* Kb = Ks + cur * 8192;
    const u16* Vb = Vs + cur * 8192;
    // S = Q K^T
    f32x4 S[4] = {};
#pragma unroll
    for (int ks = 0; ks < 4; ks++) {
      bf16x8 kf[4];
#pragma unroll
      for (int kvf = 0; kvf < 4; kvf++) {
        int kr = kvf * 16 + c;
        int slx = (ks * 4 + hh) ^ (kr & 7);
        kf[kvf] = *(const bf16x8*)(Kb + kr * 128 + slx * 8);
      }
#pragma unroll
      for (int kvf = 0; kvf < 4; kvf++)
        S[kvf] = mfma16(Qf[ks], kf[kvf], S[kvf]);
    }
    // causal mask (only near diagonal)
    if (t * 64 + 63 > START_POS + qw0) {
#pragma unroll
      for (int kvf = 0; kvf < 4; kvf++)
#pragma unroll
        for (int i = 0; i < 4; i++) {
          int kv = t * 64 + kvf * 16 + c;
          int qi = qw0 + hh * 4 + i;
          if (kv > START_POS + qi) S[kvf][i] = -1e30f;
        }
    }
    // online softmax (reduce over k: regs kvf + lanes c within 16-lane groups)
    {
      float mt[4], al[4], rs[4];
#pragma unroll
      for (int i = 0; i < 4; i++)
        mt[i] = fmaxf(fmaxf(S[0][i], S[1][i]), fmaxf(S[2][i], S[3][i]));
#pragma unroll
      for (int m = 1; m < 16; m <<= 1)
#pragma unroll
        for (int i = 0; i < 4; i++)
          mt[i] = fmaxf(mt[i], __shfl_xor(mt[i], m));
#pragma unroll
      for (int i = 0; i < 4; i++) {
        float Mn = fmaxf(Mx[i], mt[i]);
        al[i] = exp2f((Mx[i] - Mn) * C2);
        Mx[i] = Mn;
        rs[i] = 0.f;
      }
#pragma unroll
      for (int kvf = 0; kvf < 4; kvf++)
#pragma unroll
        for (int i = 0; i < 4; i++) {
          float p = exp2f((S[kvf][i] - Mx[i]) * C2);
          rs[i] += p;
          int prow = hh * 4 + i;
          int pb = prow * 160 + ((kvf * 32 + c * 2) ^ ((prow & 7) << 4));
          *(u16*)((char*)Pw + pb) = f2bf(p);
        }
#pragma unroll
      for (int m = 1; m < 16; m <<= 1)
#pragma unroll
        for (int i = 0; i < 4; i++)
          rs[i] += __shfl_xor(rs[i], m);
#pragma unroll
      for (int i = 0; i < 4; i++)
        Ls[i] = Ls[i] * al[i] + rs[i];
#pragma unroll
      for (int dt = 0; dt < 8; dt++)
#pragma unroll
        for (int i = 0; i < 4; i++)
          O[dt][i] *= al[i];
    }
    // wave-local P exchange through LDS
    asm volatile("s_waitcnt lgkmcnt(0)" ::: "memory");
    __builtin_amdgcn_sched_barrier(0);
    // O += P V
#pragma unroll
    for (int ks2 = 0; ks2 < 2; ks2++) {
      int prow = c;
      int pb = prow * 160 + ((ks2 * 64 + hh * 16) ^ ((prow & 7) << 4));
      bf16x8 pa = *(const bf16x8*)((const char*)Pw + pb);
#pragma unroll
      for (int dt = 0; dt < 8; dt++) {
        int d = dt * 16 + c;
        int slx = (ks2 * 4 + hh) ^ (d & 7);
        bf16x8 vf = *(const bf16x8*)(Vb + d * 64 + slx * 8);
        O[dt] = mfma16(pa, vf, O[dt]);
      }
    }
    __syncthreads();  // drains vmcnt(0) (prefetch done) + all waves finished with bufs
    cur ^= 1;
  }
#undef STAGE_KV
  // epilogue: ctx = O / L -> bf16 [s][h*128+d]
  {
    float inv[4];
#pragma unroll
    for (int i = 0; i < 4; i++) inv[i] = 1.0f / Ls[i];
#pragma unroll
    for (int dt = 0; dt < 8; dt++)
#pragma unroll
      for (int i = 0; i < 4; i++) {
        int qrow = qw0 + hh * 4 + i;
        int col = h * 128 + dt * 16 + c;
        ctxb[(size_t)qrow * 4096 + col] = f2bf(O[dt][i] * inv[i]);
      }
  }
}

extern "C" void kernel_launch(void* const* d_in, const int* in_sizes, int n_in,
                              void* d_out, int out_size, void* d_ws, size_t ws_size,
                              hipStream_t stream) {
  const float* x      = (const float*)d_in[0];
  const float* cosb   = (const float*)d_in[2];
  const float* sinb   = (const float*)d_in[3];
  const float* prev_k = (const float*)d_in[5];
  const float* prev_v = (const float*)d_in[6];
  const float* Wq     = (const float*)d_in[7];
  const float* Wk     = (const float*)d_in[8];
  const float* Wv     = (const float*)d_in[9];
  const float* Wo     = (const float*)d_in[10];

  // workspace layout (~151 MB)
  u16* Wt_proj = (u16*)d_ws;                                  // [6144][4096] bf16
  u16* Wt_out  = Wt_proj + (size_t)6144 * 4096;               // [4096][4096] bf16
  u16* xb      = Wt_out + (size_t)4096 * 4096;                // [1024][4096] bf16
  float* qkv   = (float*)(xb + (size_t)1024 * 4096);          // [1024][6144] f32
  u16* qb      = (u16*)(qkv + (size_t)1024 * 6144);           // [32][1024][128]
  u16* kbb     = qb + (size_t)32 * 1024 * 128;                // [8][4096][128]
  u16* vT      = kbb + (size_t)8 * 4096 * 128;                // [8][128][4096]
  u16* ctxb    = vT + (size_t)8 * 4096 * 128;                 // [1024][4096]

  float* outp   = (float*)d_out;
  float* keys   = outp + (size_t)4194304;
  float* values = outp + (size_t)8388608;

  wtrans<<<4096, 256, 0, stream>>>(Wq, Wt_proj, 4096, 64, 0);
  wtrans<<<1024, 256, 0, stream>>>(Wk, Wt_proj, 1024, 16, 4096);
  wtrans<<<1024, 256, 0, stream>>>(Wv, Wt_proj, 1024, 16, 5120);
  wtrans<<<4096, 256, 0, stream>>>(Wo, Wt_out, 4096, 64, 0);
  cvt_bf16<<<4096, 256, 0, stream>>>(x, xb, 1048576);

  gemm_bt<<<384, 256, 0, stream>>>(xb, Wt_proj, qkv, 6144, 4096, 48);

  rope_q<<<2048, 256, 0, stream>>>(qkv, cosb, sinb, qb);
  rope_k<<<512, 256, 0, stream>>>(qkv, cosb, sinb, keys, kbb);
  copy_vnew<<<1024, 256, 0, stream>>>(qkv, values);
  prev_copy<<<3072, 256, 0, stream>>>(prev_k, prev_v, keys, values, kbb);
  vtrans<<<1024, 256, 0, stream>>>(prev_v, qkv, vT);

  attn_fwd<<<512, 256, 0, stream>>>(qb, kbb, vT, ctxb);

  gemm_bt<<<256, 256, 0, stream>>>(ctxb, Wt_out, outp, 4096, 4096, 32);
}